// Round 6
// baseline (58.636 us; speedup 1.0000x reference)
//
#include <hip/hip_runtime.h>
#include <math.h>

#define N_CONS  100000
#define N_VARS  200000
#define N_EDGES 8000000
#define N_CAND  20000
#define C_FEAT  5
#define V_FEAT  19
#define BM_WORDS      6250
#define BM_WORDS_PAD  6400          // pad for vector copies
#define ACC_SLOTS     20000         // max distinct candidates = N_CAND
#define EDGE_BLOCKS   256           // 1 per CU
#define KSLICES       8
#define KS_LEN        (EDGE_BLOCKS / KSLICES)   // 32
#define CID_BLOCKS    ((ACC_SLOTS + 255) / 256) // 79

// Pack variable[:,5], constraint[:,2] into dense L2-resident arrays and
// build the candidate bitmap.
__global__ void pack_kernel(const float* __restrict__ variable,
                            const float* __restrict__ constraint,
                            const int* __restrict__ cand,
                            float* __restrict__ var5,
                            float* __restrict__ cons2,
                            unsigned int* __restrict__ bitmap) {
    int i = blockIdx.x * blockDim.x + threadIdx.x;
    if (i < N_VARS) var5[i]  = variable[i * V_FEAT + 5];
    if (i < N_CONS) cons2[i] = constraint[i * C_FEAT + 2];
    if (i < N_CAND) {
        int v = cand[i];
        atomicOr(&bitmap[v >> 5], 1u << (v & 31));
    }
}

// Build fused table bp[w] = {bitmap word, exclusive popcount prefix}.
// One ds_read_b64 in the edge loop then yields BOTH the keep-test word and
// the compact-id base (was 2 ds_read_b32 -> halves LDS-pipe pressure).
__global__ void __launch_bounds__(1024)
scan_kernel(const unsigned int* __restrict__ bitmap,
            uint2* __restrict__ bp) {
    __shared__ unsigned int s[1024];
    const int CH = 7;                                   // 7*1024 >= 6400
    int t = threadIdx.x;
    int base = t * CH;
    unsigned int w_loc[CH];
    unsigned int pf_loc[CH];
    unsigned int sum = 0;
#pragma unroll
    for (int j = 0; j < CH; ++j) {
        int w = base + j;
        unsigned int word = (w < BM_WORDS_PAD) ? bitmap[w] : 0u;
        w_loc[j]  = word;
        pf_loc[j] = sum;                                // local exclusive
        sum += __popc(word);
    }
    s[t] = sum;
    __syncthreads();
    for (int off = 1; off < 1024; off <<= 1) {          // Hillis-Steele inclusive
        unsigned int v = (t >= off) ? s[t - off] : 0u;
        __syncthreads();
        s[t] += v;
        __syncthreads();
    }
    unsigned int ebase = s[t] - sum;                    // exclusive base
#pragma unroll
    for (int j = 0; j < CH; ++j) {
        int w = base + j;
        if (w < BM_WORDS_PAD) bp[w] = make_uint2(w_loc[j], ebase + pf_loc[j]);
    }
}

// Edge phase: fused {word,prefix} table (51.2 KB) + compact accumulator
// (80 KB) in LDS. Per edge: ONE ds_read_b64 (test + cid base), branchless
// pinned gathers, one predicated ds_atomic. Zero global atomics; flush is
// a coalesced 80 KB store per block.
__global__ void __launch_bounds__(1024)
edge_kernel(const int* __restrict__ c_idx,
            const int* __restrict__ v_idx,
            const float* __restrict__ edge_attr,
            const float* __restrict__ var5,
            const float* __restrict__ cons2,
            const uint2* __restrict__ bp,
            float* __restrict__ partials) {
    __shared__ uint2 lds_bp[BM_WORDS_PAD];
    __shared__ float lds_acc[ACC_SLOTS];

    // Coalesced LDS fills.
    {
        const uint4* src = (const uint4*)bp;
        uint4* dst = (uint4*)lds_bp;
        for (int j = threadIdx.x; j < BM_WORDS_PAD / 2; j += blockDim.x)
            dst[j] = src[j];
        for (int j = threadIdx.x; j < ACC_SLOTS; j += blockDim.x)
            lds_acc[j] = 0.0f;
    }
    __syncthreads();

    const int nch = N_EDGES / 8;            // 8 edges per chunk
    int stride = gridDim.x * blockDim.x;
    const int4*   v4 = (const int4*)v_idx;
    const int4*   c4 = (const int4*)c_idx;
    const float4* e4 = (const float4*)edge_attr;

    for (int g = blockIdx.x * blockDim.x + threadIdx.x; g < nch; g += stride) {
        int4   va = v4[2 * g],     vb = v4[2 * g + 1];
        int4   ca = c4[2 * g],     cb = c4[2 * g + 1];
        float4 ea = e4[2 * g],     eb = e4[2 * g + 1];

#define PROC(vv, cc, ee)                                                     \
        {                                                                    \
            uint2 e2 = lds_bp[(vv) >> 5];                                    \
            bool keep = (e2.x >> ((vv) & 31)) & 1u;                          \
            int gv = keep ? (vv) : 0, gc = keep ? (cc) : 0;                  \
            float m = var5[gv] * (ee) + cons2[gc];                           \
            if (keep) {                                                      \
                int cid = (int)e2.y +                                        \
                          __popc(e2.x & ((1u << ((vv) & 31)) - 1u));         \
                atomicAdd(&lds_acc[cid], m);                                 \
            }                                                                \
        }
        PROC(va.x, ca.x, ea.x)  PROC(va.y, ca.y, ea.y)
        PROC(va.z, ca.z, ea.z)  PROC(va.w, ca.w, ea.w)
        PROC(vb.x, cb.x, eb.x)  PROC(vb.y, cb.y, eb.y)
        PROC(vb.z, cb.z, eb.z)  PROC(vb.w, cb.w, eb.w)
#undef PROC
    }
    __syncthreads();

    // Coalesced flush: partials[block][0..ACC_SLOTS)
    {
        float4* dst = (float4*)(partials + (size_t)blockIdx.x * ACC_SLOTS);
        const float4* src = (const float4*)lds_acc;
        for (int j = threadIdx.x; j < ACC_SLOTS / 4; j += blockDim.x)
            dst[j] = src[j];
    }
}

// Stage-1 reduce: p2[ks][cid] = sum over k in slice ks of partials[k][cid].
__global__ void reduce1_kernel(const float* __restrict__ partials,
                               float* __restrict__ p2) {
    int cb = blockIdx.x % CID_BLOCKS;
    int ks = blockIdx.x / CID_BLOCKS;
    int cid = cb * 256 + threadIdx.x;
    if (cid >= ACC_SLOTS) return;
    float acc = 0.0f;
#pragma unroll
    for (int k = 0; k < KS_LEN; ++k)
        acc += partials[(size_t)(ks * KS_LEN + k) * ACC_SLOTS + cid];
    p2[(size_t)ks * ACC_SLOTS + cid] = acc;
}

// out[i] = agg * variable[v,0] + sqrt(abs(variable[v,3])), v = cand[i]
__global__ void out_kernel(const int* __restrict__ cand,
                           const float* __restrict__ p2,
                           const uint2* __restrict__ bp,
                           const float* __restrict__ variable,
                           float* __restrict__ out) {
    int i = blockIdx.x * blockDim.x + threadIdx.x;
    if (i >= N_CAND) return;
    int v = cand[i];
    uint2 e2 = bp[v >> 5];
    int cid = (int)e2.y + __popc(e2.x & ((1u << (v & 31)) - 1u));
    float acc = 0.0f;
#pragma unroll
    for (int s = 0; s < KSLICES; ++s)
        acc += p2[(size_t)s * ACC_SLOTS + cid];
    out[i] = acc * variable[v * V_FEAT + 0] + sqrtf(fabsf(variable[v * V_FEAT + 3]));
}

extern "C" void kernel_launch(void* const* d_in, const int* in_sizes, int n_in,
                              void* d_out, int out_size, void* d_ws, size_t ws_size,
                              hipStream_t stream) {
    const float* constraint = (const float*)d_in[0];   // [N_CONS, 5]
    const float* variable   = (const float*)d_in[1];   // [N_VARS, 19]
    const int*   cv_edge    = (const int*)d_in[2];     // [2, N_EDGES]
    const float* edge_attr  = (const float*)d_in[3];   // [N_EDGES]
    const int*   cand_mask  = (const int*)d_in[4];     // [N_CAND]
    float* out = (float*)d_out;

    const int* c_idx = cv_edge;            // row 0
    const int* v_idx = cv_edge + N_EDGES;  // row 1

    // ws layout (16B-aligned):
    // var5[200000] f | cons2[100000] f | bitmap[6400] u32 | bp[6400] uint2 |
    // partials[256*20000] f | p2[8*20000] f
    float* var5  = (float*)d_ws;
    float* cons2 = var5 + N_VARS;
    unsigned int* bitmap = (unsigned int*)(cons2 + N_CONS);
    uint2* bp            = (uint2*)(bitmap + BM_WORDS_PAD);
    float* partials      = (float*)(bp + BM_WORDS_PAD);
    float* p2            = partials + (size_t)EDGE_BLOCKS * ACC_SLOTS;

    // Only the bitmap needs zeroing (everything else fully overwritten).
    hipMemsetAsync(bitmap, 0, BM_WORDS_PAD * sizeof(unsigned int), stream);

    {
        int threads = 256;
        int blocks = (N_VARS + threads - 1) / threads;
        pack_kernel<<<blocks, threads, 0, stream>>>(variable, constraint, cand_mask,
                                                    var5, cons2, bitmap);
    }
    scan_kernel<<<1, 1024, 0, stream>>>(bitmap, bp);
    edge_kernel<<<EDGE_BLOCKS, 1024, 0, stream>>>(c_idx, v_idx, edge_attr,
                                                  var5, cons2, bp, partials);
    reduce1_kernel<<<CID_BLOCKS * KSLICES, 256, 0, stream>>>(partials, p2);
    {
        int threads = 256;
        int blocks = (N_CAND + threads - 1) / threads;
        out_kernel<<<blocks, threads, 0, stream>>>(cand_mask, p2, bp, variable, out);
    }
}

// Round 7
// 57.420 us; speedup vs baseline: 1.0212x; 1.0212x over previous
//
#include <hip/hip_runtime.h>
#include <math.h>

#define N_CONS  100000
#define N_VARS  200000
#define N_EDGES 8000000
#define N_CAND  20000
#define C_FEAT  5
#define V_FEAT  19
#define BM_WORDS      6250
#define BM_WORDS_PAD  6400          // pad for vector copies
#define ACC_SLOTS     20000         // max distinct candidates = N_CAND
#define EDGE_BLOCKS   256           // 1 per CU
#define KSLICES       8
#define KS_LEN        (EDGE_BLOCKS / KSLICES)   // 32
#define CID_BLOCKS    ((ACC_SLOTS + 255) / 256) // 79

// Pack variable[:,5], constraint[:,2] into dense L2-resident arrays and
// build the candidate bitmap.
__global__ void pack_kernel(const float* __restrict__ variable,
                            const float* __restrict__ constraint,
                            const int* __restrict__ cand,
                            float* __restrict__ var5,
                            float* __restrict__ cons2,
                            unsigned int* __restrict__ bitmap) {
    int i = blockIdx.x * blockDim.x + threadIdx.x;
    if (i < N_VARS) var5[i]  = variable[i * V_FEAT + 5];
    if (i < N_CONS) cons2[i] = constraint[i * C_FEAT + 2];
    if (i < N_CAND) {
        int v = cand[i];
        atomicOr(&bitmap[v >> 5], 1u << (v & 31));
    }
}

// Fused table bp[w] = {bitmap word, exclusive popcount prefix}.
// Wave-shuffle two-level scan: 2 barriers instead of 20.
__global__ void __launch_bounds__(1024)
scan_kernel(const unsigned int* __restrict__ bitmap,
            uint2* __restrict__ bp) {
    __shared__ unsigned int wsum[16];
    const int CH = 7;                                   // 7*1024 >= 6400
    int t = threadIdx.x;
    int lane = t & 63, wid = t >> 6;
    int base = t * CH;
    unsigned int w_loc[CH];
    unsigned int pf_loc[CH];
    unsigned int sum = 0;
#pragma unroll
    for (int j = 0; j < CH; ++j) {
        int w = base + j;
        unsigned int word = (w < BM_WORDS_PAD) ? bitmap[w] : 0u;
        w_loc[j]  = word;
        pf_loc[j] = sum;                                // thread-local exclusive
        sum += __popc(word);
    }
    // wave-inclusive scan of per-thread sums
    unsigned int inc = sum;
#pragma unroll
    for (int off = 1; off < 64; off <<= 1) {
        unsigned int n = __shfl_up(inc, off, 64);
        if (lane >= off) inc += n;
    }
    if (lane == 63) wsum[wid] = inc;
    __syncthreads();
    if (wid == 0 && lane < 16) {                        // scan the 16 wave totals
        unsigned int v = wsum[lane];
#pragma unroll
        for (int off = 1; off < 16; off <<= 1) {
            unsigned int n = __shfl_up(v, off, 16);
            if (lane >= off) v += n;
        }
        wsum[lane] = v;                                 // inclusive across waves
    }
    __syncthreads();
    unsigned int ebase = inc - sum + (wid ? wsum[wid - 1] : 0u);
#pragma unroll
    for (int j = 0; j < CH; ++j) {
        int w = base + j;
        if (w < BM_WORDS_PAD) bp[w] = make_uint2(w_loc[j], ebase + pf_loc[j]);
    }
}

// Edge phase. KEY CHANGE vs r6: gathers + FMA + atomic are EXEC-MASKED under
// if(keep), not branchless-pinned. The TA processes divergent VMEM per lane,
// so a 64-lane "pinned" gather costs ~64 TA cycles even when 58 lanes point
// at line 0; masking to the ~6 live lanes cuts TA work ~10x. (r4-r6 all sat
// at 43-55us because every edge paid TA; only ~9.5% should.)
__global__ void __launch_bounds__(1024)
edge_kernel(const int* __restrict__ c_idx,
            const int* __restrict__ v_idx,
            const float* __restrict__ edge_attr,
            const float* __restrict__ var5,
            const float* __restrict__ cons2,
            const uint2* __restrict__ bp,
            float* __restrict__ partials) {
    __shared__ uint2 lds_bp[BM_WORDS_PAD];
    __shared__ float lds_acc[ACC_SLOTS];

    // Coalesced LDS fills.
    {
        const uint4* src = (const uint4*)bp;
        uint4* dst = (uint4*)lds_bp;
        for (int j = threadIdx.x; j < BM_WORDS_PAD / 2; j += blockDim.x)
            dst[j] = src[j];
        for (int j = threadIdx.x; j < ACC_SLOTS; j += blockDim.x)
            lds_acc[j] = 0.0f;
    }
    __syncthreads();

    const int nch = N_EDGES / 8;            // 8 edges per chunk
    int stride = gridDim.x * blockDim.x;
    const int4*   v4 = (const int4*)v_idx;
    const int4*   c4 = (const int4*)c_idx;
    const float4* e4 = (const float4*)edge_attr;

    for (int g = blockIdx.x * blockDim.x + threadIdx.x; g < nch; g += stride) {
        int4   va = v4[2 * g],     vb = v4[2 * g + 1];
        int4   ca = c4[2 * g],     cb = c4[2 * g + 1];
        float4 ea = e4[2 * g],     eb = e4[2 * g + 1];

#define PROC(vv, cc, ee)                                                     \
        {                                                                    \
            uint2 e2 = lds_bp[(vv) >> 5];                                    \
            if ((e2.x >> ((vv) & 31)) & 1u) {                                \
                int cid = (int)e2.y +                                        \
                          __popc(e2.x & ((1u << ((vv) & 31)) - 1u));         \
                atomicAdd(&lds_acc[cid],                                     \
                          var5[vv] * (ee) + cons2[cc]);                      \
            }                                                                \
        }
        PROC(va.x, ca.x, ea.x)  PROC(va.y, ca.y, ea.y)
        PROC(va.z, ca.z, ea.z)  PROC(va.w, ca.w, ea.w)
        PROC(vb.x, cb.x, eb.x)  PROC(vb.y, cb.y, eb.y)
        PROC(vb.z, cb.z, eb.z)  PROC(vb.w, cb.w, eb.w)
#undef PROC
    }
    __syncthreads();

    // Coalesced flush: partials[block][0..ACC_SLOTS)
    {
        float4* dst = (float4*)(partials + (size_t)blockIdx.x * ACC_SLOTS);
        const float4* src = (const float4*)lds_acc;
        for (int j = threadIdx.x; j < ACC_SLOTS / 4; j += blockDim.x)
            dst[j] = src[j];
    }
}

// Stage-1 reduce: p2[ks][cid] = sum over k in slice ks of partials[k][cid].
__global__ void reduce1_kernel(const float* __restrict__ partials,
                               float* __restrict__ p2) {
    int cb = blockIdx.x % CID_BLOCKS;
    int ks = blockIdx.x / CID_BLOCKS;
    int cid = cb * 256 + threadIdx.x;
    if (cid >= ACC_SLOTS) return;
    float acc = 0.0f;
#pragma unroll
    for (int k = 0; k < KS_LEN; ++k)
        acc += partials[(size_t)(ks * KS_LEN + k) * ACC_SLOTS + cid];
    p2[(size_t)ks * ACC_SLOTS + cid] = acc;
}

// out[i] = agg * variable[v,0] + sqrt(abs(variable[v,3])), v = cand[i]
__global__ void out_kernel(const int* __restrict__ cand,
                           const float* __restrict__ p2,
                           const uint2* __restrict__ bp,
                           const float* __restrict__ variable,
                           float* __restrict__ out) {
    int i = blockIdx.x * blockDim.x + threadIdx.x;
    if (i >= N_CAND) return;
    int v = cand[i];
    uint2 e2 = bp[v >> 5];
    int cid = (int)e2.y + __popc(e2.x & ((1u << (v & 31)) - 1u));
    float acc = 0.0f;
#pragma unroll
    for (int s = 0; s < KSLICES; ++s)
        acc += p2[(size_t)s * ACC_SLOTS + cid];
    out[i] = acc * variable[v * V_FEAT + 0] + sqrtf(fabsf(variable[v * V_FEAT + 3]));
}

extern "C" void kernel_launch(void* const* d_in, const int* in_sizes, int n_in,
                              void* d_out, int out_size, void* d_ws, size_t ws_size,
                              hipStream_t stream) {
    const float* constraint = (const float*)d_in[0];   // [N_CONS, 5]
    const float* variable   = (const float*)d_in[1];   // [N_VARS, 19]
    const int*   cv_edge    = (const int*)d_in[2];     // [2, N_EDGES]
    const float* edge_attr  = (const float*)d_in[3];   // [N_EDGES]
    const int*   cand_mask  = (const int*)d_in[4];     // [N_CAND]
    float* out = (float*)d_out;

    const int* c_idx = cv_edge;            // row 0
    const int* v_idx = cv_edge + N_EDGES;  // row 1

    // ws layout (16B-aligned):
    // var5[200000] f | cons2[100000] f | bitmap[6400] u32 | bp[6400] uint2 |
    // partials[256*20000] f | p2[8*20000] f
    float* var5  = (float*)d_ws;
    float* cons2 = var5 + N_VARS;
    unsigned int* bitmap = (unsigned int*)(cons2 + N_CONS);
    uint2* bp            = (uint2*)(bitmap + BM_WORDS_PAD);
    float* partials      = (float*)(bp + BM_WORDS_PAD);
    float* p2            = partials + (size_t)EDGE_BLOCKS * ACC_SLOTS;

    // Only the bitmap needs zeroing (everything else fully overwritten).
    hipMemsetAsync(bitmap, 0, BM_WORDS_PAD * sizeof(unsigned int), stream);

    {
        int threads = 256;
        int blocks = (N_VARS + threads - 1) / threads;
        pack_kernel<<<blocks, threads, 0, stream>>>(variable, constraint, cand_mask,
                                                    var5, cons2, bitmap);
    }
    scan_kernel<<<1, 1024, 0, stream>>>(bitmap, bp);
    edge_kernel<<<EDGE_BLOCKS, 1024, 0, stream>>>(c_idx, v_idx, edge_attr,
                                                  var5, cons2, bp, partials);
    reduce1_kernel<<<CID_BLOCKS * KSLICES, 256, 0, stream>>>(partials, p2);
    {
        int threads = 256;
        int blocks = (N_CAND + threads - 1) / threads;
        out_kernel<<<blocks, threads, 0, stream>>>(cand_mask, p2, bp, variable, out);
    }
}

// Round 8
// 56.955 us; speedup vs baseline: 1.0295x; 1.0081x over previous
//
#include <hip/hip_runtime.h>
#include <math.h>

#define N_CONS  100000
#define N_VARS  200000
#define N_EDGES 8000000
#define N_CAND  20000
#define C_FEAT  5
#define V_FEAT  19
#define BM_WORDS      6250
#define BM_WORDS_PAD  6400          // pad for vector copies
#define ACC_SLOTS     20000         // max distinct candidates = N_CAND
#define EDGE_BLOCKS   256           // 1 per CU
#define KSLICES       8
#define KS_LEN        (EDGE_BLOCKS / KSLICES)   // 32
#define CID_BLOCKS    ((ACC_SLOTS + 255) / 256) // 79

// Pack variable[:,5], constraint[:,2] into dense L2-resident arrays and
// build the candidate bitmap.
__global__ void pack_kernel(const float* __restrict__ variable,
                            const float* __restrict__ constraint,
                            const int* __restrict__ cand,
                            float* __restrict__ var5,
                            float* __restrict__ cons2,
                            unsigned int* __restrict__ bitmap) {
    int i = blockIdx.x * blockDim.x + threadIdx.x;
    if (i < N_VARS) var5[i]  = variable[i * V_FEAT + 5];
    if (i < N_CONS) cons2[i] = constraint[i * C_FEAT + 2];
    if (i < N_CAND) {
        int v = cand[i];
        atomicOr(&bitmap[v >> 5], 1u << (v & 31));
    }
}

// Fused table bp[w] = {bitmap word, exclusive popcount prefix}.
__global__ void __launch_bounds__(1024)
scan_kernel(const unsigned int* __restrict__ bitmap,
            uint2* __restrict__ bp) {
    __shared__ unsigned int wsum[16];
    const int CH = 7;                                   // 7*1024 >= 6400
    int t = threadIdx.x;
    int lane = t & 63, wid = t >> 6;
    int base = t * CH;
    unsigned int w_loc[CH];
    unsigned int pf_loc[CH];
    unsigned int sum = 0;
#pragma unroll
    for (int j = 0; j < CH; ++j) {
        int w = base + j;
        unsigned int word = (w < BM_WORDS_PAD) ? bitmap[w] : 0u;
        w_loc[j]  = word;
        pf_loc[j] = sum;                                // thread-local exclusive
        sum += __popc(word);
    }
    unsigned int inc = sum;
#pragma unroll
    for (int off = 1; off < 64; off <<= 1) {
        unsigned int n = __shfl_up(inc, off, 64);
        if (lane >= off) inc += n;
    }
    if (lane == 63) wsum[wid] = inc;
    __syncthreads();
    if (wid == 0 && lane < 16) {
        unsigned int v = wsum[lane];
#pragma unroll
        for (int off = 1; off < 16; off <<= 1) {
            unsigned int n = __shfl_up(v, off, 16);
            if (lane >= off) v += n;
        }
        wsum[lane] = v;
    }
    __syncthreads();
    unsigned int ebase = inc - sum + (wid ? wsum[wid - 1] : 0u);
#pragma unroll
    for (int j = 0; j < CH; ++j) {
        int w = base + j;
        if (w < BM_WORDS_PAD) bp[w] = make_uint2(w_loc[j], ebase + pf_loc[j]);
    }
}

// Edge phase. KEY CHANGE vs r7: explicit register ping-pong prefetch.
// r5-r7 all sat at ~43us = ~6.7K cyc/wave-iter vs ~600 cyc of issue work:
// exposed load latency, serialized per grid-stride iteration (only 4
// waves/SIMD at 131KB LDS). Now iteration N+1's 6 stream loads are issued
// BEFORE processing iteration N, and iteration 0's loads are issued before
// the LDS fill+barrier -- every vmcnt wait has a processing phase under it.
__global__ void __launch_bounds__(1024, 4)
edge_kernel(const int* __restrict__ c_idx,
            const int* __restrict__ v_idx,
            const float* __restrict__ edge_attr,
            const float* __restrict__ var5,
            const float* __restrict__ cons2,
            const uint2* __restrict__ bp,
            float* __restrict__ partials) {
    __shared__ uint2 lds_bp[BM_WORDS_PAD];
    __shared__ float lds_acc[ACC_SLOTS];

    const int nch = N_EDGES / 8;            // 8 edges per chunk
    const int stride = gridDim.x * blockDim.x;
    const int4*   v4 = (const int4*)v_idx;
    const int4*   c4 = (const int4*)c_idx;
    const float4* e4 = (const float4*)edge_attr;

    int g = blockIdx.x * blockDim.x + threadIdx.x;

    int4   vaA, vbA, caA, cbA;  float4 eaA, ebA;
    int4   vaB, vbB, caB, cbB;  float4 eaB, ebB;

#define LOADSET(VA, VB, CA, CB, EA, EB, gg)                                  \
        VA = v4[2 * (gg)];  VB = v4[2 * (gg) + 1];                           \
        CA = c4[2 * (gg)];  CB = c4[2 * (gg) + 1];                           \
        EA = e4[2 * (gg)];  EB = e4[2 * (gg) + 1];

    // Iter-0 loads issued BEFORE the fill: latency hides under fill+barrier.
    if (g < nch) { LOADSET(vaA, vbA, caA, cbA, eaA, ebA, g) }

    {
        const uint4* src = (const uint4*)bp;
        uint4* dst = (uint4*)lds_bp;
        for (int j = threadIdx.x; j < BM_WORDS_PAD / 2; j += blockDim.x)
            dst[j] = src[j];
        for (int j = threadIdx.x; j < ACC_SLOTS; j += blockDim.x)
            lds_acc[j] = 0.0f;
    }
    __syncthreads();

#define PROC(vv, cc, ee)                                                     \
        {                                                                    \
            uint2 e2 = lds_bp[(vv) >> 5];                                    \
            if ((e2.x >> ((vv) & 31)) & 1u) {                                \
                int cid = (int)e2.y +                                        \
                          __popc(e2.x & ((1u << ((vv) & 31)) - 1u));         \
                atomicAdd(&lds_acc[cid],                                     \
                          var5[vv] * (ee) + cons2[cc]);                      \
            }                                                                \
        }
#define PROC8(VA, VB, CA, CB, EA, EB)                                        \
        PROC(VA.x, CA.x, EA.x)  PROC(VA.y, CA.y, EA.y)                       \
        PROC(VA.z, CA.z, EA.z)  PROC(VA.w, CA.w, EA.w)                       \
        PROC(VB.x, CB.x, EB.x)  PROC(VB.y, CB.y, EB.y)                       \
        PROC(VB.z, CB.z, EB.z)  PROC(VB.w, CB.w, EB.w)

    int gB = g + stride;
    while (g < nch) {
        // prefetch next chunk into B, then process A (covers B's latency)
        if (gB < nch) { LOADSET(vaB, vbB, caB, cbB, eaB, ebB, gB) }
        PROC8(vaA, vbA, caA, cbA, eaA, ebA)
        g = gB + stride;
        if (gB >= nch) break;
        // prefetch into A, process B
        if (g < nch) { LOADSET(vaA, vbA, caA, cbA, eaA, ebA, g) }
        PROC8(vaB, vbB, caB, cbB, eaB, ebB)
        gB = g + stride;
    }
#undef PROC8
#undef PROC
#undef LOADSET
    __syncthreads();

    // Coalesced flush: partials[block][0..ACC_SLOTS)
    {
        float4* dst = (float4*)(partials + (size_t)blockIdx.x * ACC_SLOTS);
        const float4* src = (const float4*)lds_acc;
        for (int j = threadIdx.x; j < ACC_SLOTS / 4; j += blockDim.x)
            dst[j] = src[j];
    }
}

// Stage-1 reduce: p2[ks][cid] = sum over k in slice ks of partials[k][cid].
__global__ void reduce1_kernel(const float* __restrict__ partials,
                               float* __restrict__ p2) {
    int cb = blockIdx.x % CID_BLOCKS;
    int ks = blockIdx.x / CID_BLOCKS;
    int cid = cb * 256 + threadIdx.x;
    if (cid >= ACC_SLOTS) return;
    float acc = 0.0f;
#pragma unroll
    for (int k = 0; k < KS_LEN; ++k)
        acc += partials[(size_t)(ks * KS_LEN + k) * ACC_SLOTS + cid];
    p2[(size_t)ks * ACC_SLOTS + cid] = acc;
}

// out[i] = agg * variable[v,0] + sqrt(abs(variable[v,3])), v = cand[i]
__global__ void out_kernel(const int* __restrict__ cand,
                           const float* __restrict__ p2,
                           const uint2* __restrict__ bp,
                           const float* __restrict__ variable,
                           float* __restrict__ out) {
    int i = blockIdx.x * blockDim.x + threadIdx.x;
    if (i >= N_CAND) return;
    int v = cand[i];
    uint2 e2 = bp[v >> 5];
    int cid = (int)e2.y + __popc(e2.x & ((1u << (v & 31)) - 1u));
    float acc = 0.0f;
#pragma unroll
    for (int s = 0; s < KSLICES; ++s)
        acc += p2[(size_t)s * ACC_SLOTS + cid];
    out[i] = acc * variable[v * V_FEAT + 0] + sqrtf(fabsf(variable[v * V_FEAT + 3]));
}

extern "C" void kernel_launch(void* const* d_in, const int* in_sizes, int n_in,
                              void* d_out, int out_size, void* d_ws, size_t ws_size,
                              hipStream_t stream) {
    const float* constraint = (const float*)d_in[0];   // [N_CONS, 5]
    const float* variable   = (const float*)d_in[1];   // [N_VARS, 19]
    const int*   cv_edge    = (const int*)d_in[2];     // [2, N_EDGES]
    const float* edge_attr  = (const float*)d_in[3];   // [N_EDGES]
    const int*   cand_mask  = (const int*)d_in[4];     // [N_CAND]
    float* out = (float*)d_out;

    const int* c_idx = cv_edge;            // row 0
    const int* v_idx = cv_edge + N_EDGES;  // row 1

    // ws layout (16B-aligned):
    // var5[200000] f | cons2[100000] f | bitmap[6400] u32 | bp[6400] uint2 |
    // partials[256*20000] f | p2[8*20000] f
    float* var5  = (float*)d_ws;
    float* cons2 = var5 + N_VARS;
    unsigned int* bitmap = (unsigned int*)(cons2 + N_CONS);
    uint2* bp            = (uint2*)(bitmap + BM_WORDS_PAD);
    float* partials      = (float*)(bp + BM_WORDS_PAD);
    float* p2            = partials + (size_t)EDGE_BLOCKS * ACC_SLOTS;

    // Only the bitmap needs zeroing (everything else fully overwritten).
    hipMemsetAsync(bitmap, 0, BM_WORDS_PAD * sizeof(unsigned int), stream);

    {
        int threads = 256;
        int blocks = (N_VARS + threads - 1) / threads;
        pack_kernel<<<blocks, threads, 0, stream>>>(variable, constraint, cand_mask,
                                                    var5, cons2, bitmap);
    }
    scan_kernel<<<1, 1024, 0, stream>>>(bitmap, bp);
    edge_kernel<<<EDGE_BLOCKS, 1024, 0, stream>>>(c_idx, v_idx, edge_attr,
                                                  var5, cons2, bp, partials);
    reduce1_kernel<<<CID_BLOCKS * KSLICES, 256, 0, stream>>>(partials, p2);
    {
        int threads = 256;
        int blocks = (N_CAND + threads - 1) / threads;
        out_kernel<<<blocks, threads, 0, stream>>>(cand_mask, p2, bp, variable, out);
    }
}